// Round 2
// baseline (314.397 us; speedup 1.0000x reference)
//
#include <hip/hip_runtime.h>
#include <hip/hip_bf16.h>
#include <hip/hip_cooperative_groups.h>

namespace cg = cooperative_groups;

// B=512, I=1152, K=8, L=16, O=7; IK=9216, LO=112.
// Round-1 restructure: 6 dispatches -> 2.
//   prep0: x->xbf,xT (bf16) + wpT/wps = bf16(w) padded (STATIC) + Z init
//   route: ONE persistent cooperative kernel (256 blocks x 1024 thr,
//          1 block/CU) running the full 3-iteration routing loop with
//          grid.sync() between phases:
//            sq(it): s = xbf . wps (16-way K-split, LDS reduce), Z-divide,
//                    squash -> vT (+out on it==2)
//            g(it):  G = xT.vT MFMA -> w-contract -> bij -> cs=exp ->
//                    Z[it+1] + wps rescale (block owns i=8*bid..+8)
//          Each block keeps its (mt,ng) tile on the SAME CU/XCD across all
//          iterations -> A-slices/wps stay L2-warm; no inter-dispatch drains.
// Softmax deferred: wps carries unnormalized exp, sq divides by Z_l.
// wps pad rows (o==7) are exact zeros. Iter-3 bij update dead -> skipped.

#define NB 512
#define NI 1152
#define NLO 112
#define NIK 9216
#define NPAD 128             // padded N: n = l*8+o, o==7 is zero pad

typedef __attribute__((ext_vector_type(8))) short bf16x8;
typedef __attribute__((ext_vector_type(4))) float f32x4;

__device__ __forceinline__ ushort f2bf(float f) {
    __hip_bfloat16 h = __float2bfloat16(f);
    return *(ushort*)&h;
}
__device__ __forceinline__ float bf2f(short s) {
    union { unsigned int u; float f; } v;
    v.u = ((unsigned int)(unsigned short)s) << 16;
    return v.f;
}

// ---- conv_x body: x fp32 -> xbf [b][ik] and xT [ik][b], both bf16 ----
__device__ __forceinline__ void conv_x_body(const float* __restrict__ x,
                                            ushort* __restrict__ xbf,
                                            ushort* __restrict__ xT, int bid) {
    __shared__ ushort tile[64][68];
    int kg = bid % 144, bg = bid / 144;
    int k0 = kg * 64, b0 = bg * 64;
    int t = threadIdx.x;
    for (int e = t; e < 1024; e += 256) {
        int r = e >> 4, c4 = (e & 15) * 4;
        float4 f = *(const float4*)&x[(size_t)(b0 + r) * NIK + k0 + c4];
        ushort4 u = { f2bf(f.x), f2bf(f.y), f2bf(f.z), f2bf(f.w) };
        *(ushort4*)&xbf[(size_t)(b0 + r) * NIK + k0 + c4] = u;
        tile[r][c4] = u.x; tile[r][c4 + 1] = u.y; tile[r][c4 + 2] = u.z; tile[r][c4 + 3] = u.w;
    }
    __syncthreads();
    for (int e = t; e < 1024; e += 256) {
        int kr = e >> 4, c4 = (e & 15) * 4;
        ushort4 u = { tile[c4][kr], tile[c4 + 1][kr], tile[c4 + 2][kr], tile[c4 + 3][kr] };
        *(ushort4*)&xT[(size_t)(k0 + kr) * NB + b0 + c4] = u;
    }
}

// ---- prep0: conv_x (0..1151) + static wpT/wps build + Z init (1152..1295) ----
__global__ __launch_bounds__(256) void prep0(const float* __restrict__ x,
                                             ushort* __restrict__ xbf,
                                             ushort* __restrict__ xT,
                                             const float* __restrict__ w,
                                             ushort* __restrict__ wpT,
                                             ushort* __restrict__ wps,
                                             float* __restrict__ Z) {
    if (blockIdx.x < 1152) { conv_x_body(x, xbf, xT, blockIdx.x); return; }
    __shared__ ushort tile[NPAD][66];
    int t = threadIdx.x;
    int wb = blockIdx.x - 1152;      // 0..143
    int ik0 = wb * 64;
    if (blockIdx.x == 1152 && t < 48) Z[t] = (t < 16) ? 1152.0f : 0.0f;
    for (int e = t; e < 8192; e += 256) {
        int ikl = e >> 7, np = e & 127;
        int l = np >> 3, o = np & 7;
        float wv = (o < 7) ? w[(size_t)(ik0 + ikl) * NLO + l * 7 + o] : 0.f;
        tile[np][ikl] = f2bf(wv);
    }
    __syncthreads();
    for (int e = t; e < 8192; e += 256) {
        int np = e >> 6, ikl = e & 63;
        ushort v = tile[np][ikl];
        wpT[(size_t)np * NIK + ik0 + ikl] = v;   // static master copy
        wps[(size_t)np * NIK + ik0 + ikl] = v;   // iter-0 scaled copy (eb=1)
    }
}

// ---- route: persistent cooperative kernel, full routing loop ----
// 256 blocks x 1024 thr, exactly 1 block/CU (launch_bounds caps VGPR at 128).
// sq geometry: block (mt=bid&31, ng=bid>>5) -> 16 b-rows x 16 n-cols,
//   16 waves K-split 9216/16=576. blocks sharing an xbf M-slice are
//   bid%32-equal -> same XCD (bid%8 pattern).
// g geometry: blocks 0..143, 16 waves = 4 ik-tiles x 4 B-quarters.
__global__ __launch_bounds__(1024, 4) void route(const ushort* __restrict__ xbf,
                                                 ushort* __restrict__ wps,
                                                 float* __restrict__ Z,
                                                 ushort* __restrict__ vT,
                                                 float* __restrict__ out,
                                                 const ushort* __restrict__ xT,
                                                 const float* __restrict__ w,
                                                 float* __restrict__ bij,
                                                 const ushort* __restrict__ wpT) {
    cg::grid_group grid = cg::this_grid();
    __shared__ float sp[16][16][16];   // [wave][m][n] 16 KB
    __shared__ float ss[16][16];
    __shared__ float facs[16][2];
    __shared__ float zi[2];
    __shared__ float bs[4][8][16];
    __shared__ float cs[128];
    int bid = blockIdx.x;
    int t = threadIdx.x;
    int wv = t >> 6, lane = t & 63;
    int row = lane & 15, quad = lane >> 4;
    int mt = bid & 31, ng = bid >> 5;
    int b0 = mt * 16, n0 = ng * 16;
    int k0 = wv * 576;                 // 16-way K-split of 9216
    const ushort* ap = xbf + (size_t)(b0 + row) * NIK + k0 + quad * 8;
    const ushort* bp = wps + (size_t)(n0 + row) * NIK + k0 + quad * 8;

    for (int it = 0; it < 3; ++it) {
        // ---------------- sq phase ----------------
        if (t < 2) zi[t] = 1.0f / Z[it * 16 + ng * 2 + t];
        f32x4 acc = {0.f, 0.f, 0.f, 0.f};
        #pragma unroll
        for (int ks = 0; ks < 18; ++ks) {  // 576/32
            bf16x8 a = *(const bf16x8*)(ap + ks * 32);
            bf16x8 b = *(const bf16x8*)(bp + ks * 32);
            acc = __builtin_amdgcn_mfma_f32_16x16x32_bf16(a, b, acc, 0, 0, 0);
        }
        #pragma unroll
        for (int r = 0; r < 4; ++r) sp[wv][quad * 4 + r][row] = acc[r];
        __syncthreads();
        if (t < 256) {
            int m = t >> 4, n = t & 15;
            float sv = 0.f;
            #pragma unroll
            for (int w8 = 0; w8 < 16; ++w8) sv += sp[w8][m][n];
            ss[m][n] = sv * zi[n >> 3];
        }
        __syncthreads();
        if (t < 32) {
            int m = t >> 1, ll = t & 1;
            float sq = 0.f;
            #pragma unroll
            for (int o = 0; o < 8; ++o) { float e = ss[m][ll * 8 + o]; sq += e * e; }
            facs[m][ll] = sqrtf(sq) / (1.0f + sq);   // == (sq/(1+sq))/norm; pad adds 0
        }
        __syncthreads();
        if (t < 256) {
            int m = t >> 4, n = t & 15;
            int o = n & 7, lg = ng * 2 + (n >> 3);
            if (o < 7) {
                float vv = ss[m][n] * facs[m][n >> 3];
                vT[(size_t)(o * 16 + lg) * NB + b0 + m] = f2bf(vv);
                if (it == 2) out[(size_t)(b0 + m) * NLO + o * 16 + lg] = vv;
            }
        }
        if (it == 2) break;            // uniform; no further phases
        grid.sync();

        // ---------------- g phase (blocks 0..143) ----------------
        if (bid < 144) {
            int qt = wv & 3;               // B-quarter (128 batch each)
            int mtg = wv >> 2;             // 0..3 ik-tile
            int m0 = bid * 64 + mtg * 16;
            int kb0 = qt * 128;
            const ushort* gap = xT + (size_t)(m0 + row) * NB + kb0 + quad * 8;
            const ushort* gbp = vT + (size_t)row * NB + kb0 + quad * 8;  // + nt*16*NB
            f32x4 gacc[7];
            #pragma unroll
            for (int nt = 0; nt < 7; ++nt) gacc[nt] = (f32x4){0.f, 0.f, 0.f, 0.f};
            #pragma unroll
            for (int ks = 0; ks < 4; ++ks) {                 // 128/32
                bf16x8 a = *(const bf16x8*)(gap + ks * 32);
                #pragma unroll
                for (int nt = 0; nt < 7; ++nt) {
                    bf16x8 bfr = *(const bf16x8*)(gbp + (size_t)nt * 16 * NB + ks * 32);
                    gacc[nt] = __builtin_amdgcn_mfma_f32_16x16x32_bf16(a, bfr, gacc[nt], 0, 0, 0);
                }
            }
            // lane holds G[ik = m0+quad*4+r][o*16+l], o = nt, l = row
            float S = 0.f;
            #pragma unroll
            for (int r = 0; r < 4; ++r) {
                int ik = m0 + quad * 4 + r;
                const float* wr = w + (size_t)ik * NLO + row * 7;
                float p = 0.f;
                #pragma unroll
                for (int o = 0; o < 7; ++o) p += wr[o] * gacc[o][r];
                S += p;
            }
            float Sp = __shfl_down(S, 16);                   // partner quad's 4-ik sum
            if ((quad & 1) == 0)
                bs[qt][mtg * 2 + (quad >> 1)][row] = (S + Sp) * (1.0f / 512.0f);
            __syncthreads();
            if (t < 128) {
                int il = t >> 4, l = t & 15;
                int i = bid * 8 + il;
                float val = bs[0][il][l] + bs[1][il][l] + bs[2][il][l] + bs[3][il][l];
                if (it) val += bij[i * 16 + l];
                bij[i * 16 + l] = val;
                cs[t] = expf(val);       // cs[il*16 + l]
            }
            __syncthreads();
            if (t < 16) {
                float z = 0.f;
                #pragma unroll
                for (int j = 0; j < 8; ++j) z += cs[j * 16 + t];
                atomicAdd(&Z[(it + 1) * 16 + t], z);
            }
            // rescale this block's 64 ik-columns: wps = bf16(cs * wpT).
            int ik0 = bid * 64;
            for (int e = t; e < 2048; e += 1024) {
                int np = e >> 4, i4 = (e & 15) * 4;
                float sc = cs[(i4 >> 3) * 16 + (np >> 3)];
                ushort4 wv4 = *(const ushort4*)&wpT[(size_t)np * NIK + ik0 + i4];
                ushort4 o4 = { f2bf(bf2f((short)wv4.x) * sc), f2bf(bf2f((short)wv4.y) * sc),
                               f2bf(bf2f((short)wv4.z) * sc), f2bf(bf2f((short)wv4.w) * sc) };
                *(ushort4*)&wps[(size_t)np * NIK + ik0 + i4] = o4;
            }
        }
        grid.sync();
    }
}

extern "C" void kernel_launch(void* const* d_in, const int* in_sizes, int n_in,
                              void* d_out, int out_size, void* d_ws, size_t ws_size,
                              hipStream_t stream) {
    const float* x = (const float*)d_in[0];   // [512][9216]
    const float* w = (const float*)d_in[1];   // [9216][112]
    float* out = (float*)d_out;               // [512][112]
    float* ws = (float*)d_ws;
    float*  f_bij  = ws;                                  // 18432
    float*  f_Z    = f_bij + NI * 16;                     // 3*16
    ushort* xbf    = (ushort*)(f_Z + 48);                 // 512*9216
    ushort* xT     = xbf + (size_t)NB * NIK;              // 9216*512
    ushort* wpT    = xT + (size_t)NIK * NB;               // 128*9216 static
    ushort* wps    = wpT + (size_t)NPAD * NIK;            // 128*9216 scaled
    ushort* vT     = wps + (size_t)NPAD * NIK;            // 112*512
    prep0<<<1296, 256, 0, stream>>>(x, xbf, xT, w, wpT, wps, f_Z);
    const ushort* xbf_c = xbf;
    const ushort* xT_c = xT;
    const ushort* wpT_c = wpT;
    void* args[] = { (void*)&xbf_c, (void*)&wps, (void*)&f_Z, (void*)&vT,
                     (void*)&out, (void*)&xT_c, (void*)&w, (void*)&f_bij,
                     (void*)&wpT_c };
    hipLaunchCooperativeKernel((const void*)route, dim3(256), dim3(1024),
                               args, 0, stream);
}

// Round 3
// 302.907 us; speedup vs baseline: 1.0379x; 1.0379x over previous
//
#include <hip/hip_runtime.h>
#include <hip/hip_bf16.h>
#include <hip/hip_cooperative_groups.h>

namespace cg = cooperative_groups;

// B=512, I=1152, K=8, L=16, O=7; IK=9216, LO=112.
// Round-2: identical structure to Round 1 EXCEPT the VGPR cap is removed.
// Round 1's __launch_bounds__(1024,4) forced a 64-VGPR cap -> heavy scratch
// spills (66 MB of phantom TCC writes, 99%-idle pipes, 218 us). A 16-wave
// block needs <=128 VGPR for residency; plain __launch_bounds__(1024) gives
// the allocator that budget. g-phase inner loop restructured to load-use
// interleave to keep peak liveness ~75 regs.
//   prep0: x->xbf,xT (bf16) + wpT/wps = bf16(w) padded (STATIC) + Z init
//   route: ONE persistent cooperative kernel (256 blocks x 1024 thr,
//          1 block/CU) running the full 3-iteration routing loop with
//          grid.sync() between phases.
// Softmax deferred: wps carries unnormalized exp, sq divides by Z_l.
// wps pad rows (o==7) are exact zeros. Iter-3 bij update dead -> skipped.

#define NB 512
#define NI 1152
#define NLO 112
#define NIK 9216
#define NPAD 128             // padded N: n = l*8+o, o==7 is zero pad

typedef __attribute__((ext_vector_type(8))) short bf16x8;
typedef __attribute__((ext_vector_type(4))) float f32x4;

__device__ __forceinline__ ushort f2bf(float f) {
    __hip_bfloat16 h = __float2bfloat16(f);
    return *(ushort*)&h;
}
__device__ __forceinline__ float bf2f(short s) {
    union { unsigned int u; float f; } v;
    v.u = ((unsigned int)(unsigned short)s) << 16;
    return v.f;
}

// ---- conv_x body: x fp32 -> xbf [b][ik] and xT [ik][b], both bf16 ----
__device__ __forceinline__ void conv_x_body(const float* __restrict__ x,
                                            ushort* __restrict__ xbf,
                                            ushort* __restrict__ xT, int bid) {
    __shared__ ushort tile[64][68];
    int kg = bid % 144, bg = bid / 144;
    int k0 = kg * 64, b0 = bg * 64;
    int t = threadIdx.x;
    for (int e = t; e < 1024; e += 256) {
        int r = e >> 4, c4 = (e & 15) * 4;
        float4 f = *(const float4*)&x[(size_t)(b0 + r) * NIK + k0 + c4];
        ushort4 u = { f2bf(f.x), f2bf(f.y), f2bf(f.z), f2bf(f.w) };
        *(ushort4*)&xbf[(size_t)(b0 + r) * NIK + k0 + c4] = u;
        tile[r][c4] = u.x; tile[r][c4 + 1] = u.y; tile[r][c4 + 2] = u.z; tile[r][c4 + 3] = u.w;
    }
    __syncthreads();
    for (int e = t; e < 1024; e += 256) {
        int kr = e >> 4, c4 = (e & 15) * 4;
        ushort4 u = { tile[c4][kr], tile[c4 + 1][kr], tile[c4 + 2][kr], tile[c4 + 3][kr] };
        *(ushort4*)&xT[(size_t)(k0 + kr) * NB + b0 + c4] = u;
    }
}

// ---- prep0: conv_x (0..1151) + static wpT/wps build + Z init (1152..1295) ----
__global__ __launch_bounds__(256) void prep0(const float* __restrict__ x,
                                             ushort* __restrict__ xbf,
                                             ushort* __restrict__ xT,
                                             const float* __restrict__ w,
                                             ushort* __restrict__ wpT,
                                             ushort* __restrict__ wps,
                                             float* __restrict__ Z) {
    if (blockIdx.x < 1152) { conv_x_body(x, xbf, xT, blockIdx.x); return; }
    __shared__ ushort tile[NPAD][66];
    int t = threadIdx.x;
    int wb = blockIdx.x - 1152;      // 0..143
    int ik0 = wb * 64;
    if (blockIdx.x == 1152 && t < 48) Z[t] = (t < 16) ? 1152.0f : 0.0f;
    for (int e = t; e < 8192; e += 256) {
        int ikl = e >> 7, np = e & 127;
        int l = np >> 3, o = np & 7;
        float wv = (o < 7) ? w[(size_t)(ik0 + ikl) * NLO + l * 7 + o] : 0.f;
        tile[np][ikl] = f2bf(wv);
    }
    __syncthreads();
    for (int e = t; e < 8192; e += 256) {
        int np = e >> 6, ikl = e & 63;
        ushort v = tile[np][ikl];
        wpT[(size_t)np * NIK + ik0 + ikl] = v;   // static master copy
        wps[(size_t)np * NIK + ik0 + ikl] = v;   // iter-0 scaled copy (eb=1)
    }
}

// ---- route: persistent cooperative kernel, full routing loop ----
// 256 blocks x 1024 thr, 1 block/CU (16 waves -> <=128 VGPR, no min-waves
// clause: Round 1's ",4" capped VGPR at 64 and spilled catastrophically).
// sq geometry: block (mt=bid&31, ng=bid>>5) -> 16 b-rows x 16 n-cols,
//   16 waves K-split 9216/16=576. blocks sharing an xbf M-slice are
//   bid%32-equal -> same XCD (bid%8 pattern).
// g geometry: blocks 0..143, 16 waves = 4 ik-tiles x 4 B-quarters.
__global__ __launch_bounds__(1024) void route(const ushort* __restrict__ xbf,
                                              ushort* __restrict__ wps,
                                              float* __restrict__ Z,
                                              ushort* __restrict__ vT,
                                              float* __restrict__ out,
                                              const ushort* __restrict__ xT,
                                              const float* __restrict__ w,
                                              float* __restrict__ bij,
                                              const ushort* __restrict__ wpT) {
    cg::grid_group grid = cg::this_grid();
    __shared__ float sp[16][16][16];   // [wave][m][n] 16 KB
    __shared__ float ss[16][16];
    __shared__ float facs[16][2];
    __shared__ float zi[2];
    __shared__ float bs[4][8][16];
    __shared__ float cs[128];
    int bid = blockIdx.x;
    int t = threadIdx.x;
    int wv = t >> 6, lane = t & 63;
    int row = lane & 15, quad = lane >> 4;
    int mt = bid & 31, ng = bid >> 5;
    int b0 = mt * 16, n0 = ng * 16;
    int k0 = wv * 576;                 // 16-way K-split of 9216
    const ushort* ap = xbf + (size_t)(b0 + row) * NIK + k0 + quad * 8;
    const ushort* bp = wps + (size_t)(n0 + row) * NIK + k0 + quad * 8;

    for (int it = 0; it < 3; ++it) {
        // ---------------- sq phase ----------------
        if (t < 2) zi[t] = 1.0f / Z[it * 16 + ng * 2 + t];
        f32x4 acc = {0.f, 0.f, 0.f, 0.f};
        #pragma unroll 6
        for (int ks = 0; ks < 18; ++ks) {  // 576/32
            bf16x8 a = *(const bf16x8*)(ap + ks * 32);
            bf16x8 b = *(const bf16x8*)(bp + ks * 32);
            acc = __builtin_amdgcn_mfma_f32_16x16x32_bf16(a, b, acc, 0, 0, 0);
        }
        #pragma unroll
        for (int r = 0; r < 4; ++r) sp[wv][quad * 4 + r][row] = acc[r];
        __syncthreads();
        if (t < 256) {
            int m = t >> 4, n = t & 15;
            float sv = 0.f;
            #pragma unroll
            for (int w8 = 0; w8 < 16; ++w8) sv += sp[w8][m][n];
            ss[m][n] = sv * zi[n >> 3];
        }
        __syncthreads();
        if (t < 32) {
            int m = t >> 1, ll = t & 1;
            float sq = 0.f;
            #pragma unroll
            for (int o = 0; o < 8; ++o) { float e = ss[m][ll * 8 + o]; sq += e * e; }
            facs[m][ll] = sqrtf(sq) / (1.0f + sq);   // == (sq/(1+sq))/norm; pad adds 0
        }
        __syncthreads();
        if (t < 256) {
            int m = t >> 4, n = t & 15;
            int o = n & 7, lg = ng * 2 + (n >> 3);
            if (o < 7) {
                float vv = ss[m][n] * facs[m][n >> 3];
                vT[(size_t)(o * 16 + lg) * NB + b0 + m] = f2bf(vv);
                if (it == 2) out[(size_t)(b0 + m) * NLO + o * 16 + lg] = vv;
            }
        }
        if (it == 2) break;            // uniform; no further phases
        grid.sync();

        // ---------------- g phase (blocks 0..143) ----------------
        if (bid < 144) {
            int qt = wv & 3;               // B-quarter (128 batch each)
            int mtg = wv >> 2;             // 0..3 ik-tile
            int m0 = bid * 64 + mtg * 16;
            int kb0 = qt * 128;
            const ushort* gap = xT + (size_t)(m0 + row) * NB + kb0 + quad * 8;
            const ushort* gbp = vT + (size_t)row * NB + kb0 + quad * 8;  // + nt*16*NB
            f32x4 gacc[7];
            #pragma unroll
            for (int nt = 0; nt < 7; ++nt) gacc[nt] = (f32x4){0.f, 0.f, 0.f, 0.f};
            // load-use interleave: one A-frag + one B-frag live at a time
            // (keeps peak VGPR liveness ~75; Round 1's form spilled at cap 64)
            for (int ks = 0; ks < 4; ++ks) {                 // 128/32
                bf16x8 a = *(const bf16x8*)(gap + ks * 32);
                #pragma unroll
                for (int nt = 0; nt < 7; ++nt) {
                    bf16x8 bfr = *(const bf16x8*)(gbp + (size_t)nt * 16 * NB + ks * 32);
                    gacc[nt] = __builtin_amdgcn_mfma_f32_16x16x32_bf16(a, bfr, gacc[nt], 0, 0, 0);
                }
            }
            // lane holds G[ik = m0+quad*4+r][o*16+l], o = nt, l = row
            float S = 0.f;
            #pragma unroll
            for (int r = 0; r < 4; ++r) {
                int ik = m0 + quad * 4 + r;
                const float* wr = w + (size_t)ik * NLO + row * 7;
                float p = 0.f;
                #pragma unroll
                for (int o = 0; o < 7; ++o) p += wr[o] * gacc[o][r];
                S += p;
            }
            float Sp = __shfl_down(S, 16);                   // partner quad's 4-ik sum
            if ((quad & 1) == 0)
                bs[qt][mtg * 2 + (quad >> 1)][row] = (S + Sp) * (1.0f / 512.0f);
            __syncthreads();
            if (t < 128) {
                int il = t >> 4, l = t & 15;
                int i = bid * 8 + il;
                float val = bs[0][il][l] + bs[1][il][l] + bs[2][il][l] + bs[3][il][l];
                if (it) val += bij[i * 16 + l];
                bij[i * 16 + l] = val;
                cs[t] = expf(val);       // cs[il*16 + l]
            }
            __syncthreads();
            if (t < 16) {
                float z = 0.f;
                #pragma unroll
                for (int j = 0; j < 8; ++j) z += cs[j * 16 + t];
                atomicAdd(&Z[(it + 1) * 16 + t], z);
            }
            // rescale this block's 64 ik-columns: wps = bf16(cs * wpT).
            int ik0 = bid * 64;
            for (int e = t; e < 2048; e += 1024) {
                int np = e >> 4, i4 = (e & 15) * 4;
                float sc = cs[(i4 >> 3) * 16 + (np >> 3)];
                ushort4 wv4 = *(const ushort4*)&wpT[(size_t)np * NIK + ik0 + i4];
                ushort4 o4 = { f2bf(bf2f((short)wv4.x) * sc), f2bf(bf2f((short)wv4.y) * sc),
                               f2bf(bf2f((short)wv4.z) * sc), f2bf(bf2f((short)wv4.w) * sc) };
                *(ushort4*)&wps[(size_t)np * NIK + ik0 + i4] = o4;
            }
        }
        grid.sync();
    }
}

extern "C" void kernel_launch(void* const* d_in, const int* in_sizes, int n_in,
                              void* d_out, int out_size, void* d_ws, size_t ws_size,
                              hipStream_t stream) {
    const float* x = (const float*)d_in[0];   // [512][9216]
    const float* w = (const float*)d_in[1];   // [9216][112]
    float* out = (float*)d_out;               // [512][112]
    float* ws = (float*)d_ws;
    float*  f_bij  = ws;                                  // 18432
    float*  f_Z    = f_bij + NI * 16;                     // 3*16
    ushort* xbf    = (ushort*)(f_Z + 48);                 // 512*9216
    ushort* xT     = xbf + (size_t)NB * NIK;              // 9216*512
    ushort* wpT    = xT + (size_t)NIK * NB;               // 128*9216 static
    ushort* wps    = wpT + (size_t)NPAD * NIK;            // 128*9216 scaled
    ushort* vT     = wps + (size_t)NPAD * NIK;            // 112*512
    prep0<<<1296, 256, 0, stream>>>(x, xbf, xT, w, wpT, wps, f_Z);
    const ushort* xbf_c = xbf;
    const ushort* xT_c = xT;
    const ushort* wpT_c = wpT;
    void* args[] = { (void*)&xbf_c, (void*)&wps, (void*)&f_Z, (void*)&vT,
                     (void*)&out, (void*)&xT_c, (void*)&w, (void*)&f_bij,
                     (void*)&wpT_c };
    hipLaunchCooperativeKernel((const void*)route, dim3(256), dim3(1024),
                               args, 0, stream);
}

// Round 4
// 172.654 us; speedup vs baseline: 1.8210x; 1.7544x over previous
//
#include <hip/hip_runtime.h>
#include <hip/hip_bf16.h>

// B=512, I=1152, K=8, L=16, O=7; IK=9216, LO=112.
// Round-3: revert to the 6-dispatch structure (best measured: 174 us).
// Cooperative fusion was structurally bad: each grid.sync costs ~45 us
// (cross-XCD L2 writeback-invalidate + 256-block spin), traffic-insensitive
// (R1 vs R2: +132 MB scratch traffic moved dur only 4%).
// New in this round: sq_gemm restructured for memory-level parallelism --
// 512 threads (8-wave K-split), __launch_bounds__(512,2) to break the
// 64-VGPR occupancy heuristic, and an explicit 6-deep ring prefetch
// (12 outstanding 16B loads/wave) so the 576 KB/block L2 fetch is
// BW-bound instead of latency-bound.
//   prep0: x->xbf,xT (bf16) + wpT/wps = bf16(w) padded (STATIC) + Z init
//   sq_gemm: s = xbf . wps (pre-scaled B), LDS reduce, Z-divide + squash
//            -> vT (+out last iter)
//   g_wc: G = xT.vT MFMA -> w-contract -> bij -> cs=exp -> Z + wps rescale
// Softmax deferred: wps carries unnormalized exp, sq divides by Z_l.
// wps pad rows (o==7) are exact zeros. Iter-3 bij update dead -> skipped.

#define NB 512
#define NI 1152
#define NLO 112
#define NIK 9216
#define NPAD 128             // padded N: n = l*8+o, o==7 is zero pad

typedef __attribute__((ext_vector_type(8))) short bf16x8;
typedef __attribute__((ext_vector_type(4))) float f32x4;

__device__ __forceinline__ ushort f2bf(float f) {
    __hip_bfloat16 h = __float2bfloat16(f);
    return *(ushort*)&h;
}
__device__ __forceinline__ float bf2f(short s) {
    union { unsigned int u; float f; } v;
    v.u = ((unsigned int)(unsigned short)s) << 16;
    return v.f;
}

// ---- conv_x body: x fp32 -> xbf [b][ik] and xT [ik][b], both bf16 ----
__device__ __forceinline__ void conv_x_body(const float* __restrict__ x,
                                            ushort* __restrict__ xbf,
                                            ushort* __restrict__ xT, int bid) {
    __shared__ ushort tile[64][68];
    int kg = bid % 144, bg = bid / 144;
    int k0 = kg * 64, b0 = bg * 64;
    int t = threadIdx.x;
    for (int e = t; e < 1024; e += 256) {
        int r = e >> 4, c4 = (e & 15) * 4;
        float4 f = *(const float4*)&x[(size_t)(b0 + r) * NIK + k0 + c4];
        ushort4 u = { f2bf(f.x), f2bf(f.y), f2bf(f.z), f2bf(f.w) };
        *(ushort4*)&xbf[(size_t)(b0 + r) * NIK + k0 + c4] = u;
        tile[r][c4] = u.x; tile[r][c4 + 1] = u.y; tile[r][c4 + 2] = u.z; tile[r][c4 + 3] = u.w;
    }
    __syncthreads();
    for (int e = t; e < 1024; e += 256) {
        int kr = e >> 4, c4 = (e & 15) * 4;
        ushort4 u = { tile[c4][kr], tile[c4 + 1][kr], tile[c4 + 2][kr], tile[c4 + 3][kr] };
        *(ushort4*)&xT[(size_t)(k0 + kr) * NB + b0 + c4] = u;
    }
}

// ---- prep0: conv_x (0..1151) + static wpT/wps build + Z init (1152..1295) ----
__global__ __launch_bounds__(256) void prep0(const float* __restrict__ x,
                                             ushort* __restrict__ xbf,
                                             ushort* __restrict__ xT,
                                             const float* __restrict__ w,
                                             ushort* __restrict__ wpT,
                                             ushort* __restrict__ wps,
                                             float* __restrict__ Z) {
    if (blockIdx.x < 1152) { conv_x_body(x, xbf, xT, blockIdx.x); return; }
    __shared__ ushort tile[NPAD][66];
    int t = threadIdx.x;
    int wb = blockIdx.x - 1152;      // 0..143
    int ik0 = wb * 64;
    if (blockIdx.x == 1152 && t < 48) Z[t] = (t < 16) ? 1152.0f : 0.0f;
    for (int e = t; e < 8192; e += 256) {
        int ikl = e >> 7, np = e & 127;
        int l = np >> 3, o = np & 7;
        float wv = (o < 7) ? w[(size_t)(ik0 + ikl) * NLO + l * 7 + o] : 0.f;
        tile[np][ikl] = f2bf(wv);
    }
    __syncthreads();
    for (int e = t; e < 8192; e += 256) {
        int np = e >> 6, ikl = e & 63;
        ushort v = tile[np][ikl];
        wpT[(size_t)np * NIK + ik0 + ikl] = v;   // static master copy
        wps[(size_t)np * NIK + ik0 + ikl] = v;   // iter-0 scaled copy (eb=1)
    }
}

// ---- sq_gemm: fused s-GEMM + Z-divide + squash -> vT/out ----
// 256 blocks x 512 thr (8 waves, K-split 9216/8=1152 -> 36 K-steps/wave).
// __launch_bounds__(512,2): VGPR ceiling 256 (NOT the 64-reg occupancy
// heuristic) so the 6-deep ring prefetch stays in registers: 12 outstanding
// 16B loads/wave = ~96 KB in flight/CU -> L2-BW-bound, not latency-bound.
// blocks sharing an xbf M-slice are bid%32-equal -> same XCD (bid%8).
__global__ __launch_bounds__(512, 2) void sq_gemm(const ushort* __restrict__ xbf,
                                                  const ushort* __restrict__ wps,
                                                  const float* __restrict__ Zit,
                                                  ushort* __restrict__ vT,
                                                  float* __restrict__ out, int wout) {
    __shared__ float sp[8][16][16];    // [wave][m][n] 8 KB
    __shared__ float ss[16][16];
    __shared__ float facs[16][2];
    __shared__ float zi[2];
    int bid = blockIdx.x;
    int mt = bid & 31, ng = bid >> 5;
    int b0 = mt * 16, n0 = ng * 16;
    int t = threadIdx.x;
    int wv = t >> 6, lane = t & 63;
    int row = lane & 15, quad = lane >> 4;
    int k0 = wv * 1152;                // 8-way K-split of 9216
    if (t < 2) zi[t] = 1.0f / Zit[ng * 2 + t];
    const ushort* ap = xbf + (size_t)(b0 + row) * NIK + k0 + quad * 8;
    const ushort* bp = wps + (size_t)(n0 + row) * NIK + k0 + quad * 8;
    // 6-deep ring prefetch; fully unrolled -> all ring indices static (no scratch)
    bf16x8 ab[6], bb[6];
    #pragma unroll
    for (int p = 0; p < 6; ++p) {
        ab[p] = *(const bf16x8*)(ap + p * 32);
        bb[p] = *(const bf16x8*)(bp + p * 32);
    }
    f32x4 acc = {0.f, 0.f, 0.f, 0.f};
    #pragma unroll
    for (int ks = 0; ks < 36; ++ks) {  // 1152/32
        int s = ks % 6;
        acc = __builtin_amdgcn_mfma_f32_16x16x32_bf16(ab[s], bb[s], acc, 0, 0, 0);
        if (ks < 30) {
            ab[s] = *(const bf16x8*)(ap + (ks + 6) * 32);
            bb[s] = *(const bf16x8*)(bp + (ks + 6) * 32);
        }
    }
    #pragma unroll
    for (int r = 0; r < 4; ++r) sp[wv][quad * 4 + r][row] = acc[r];
    __syncthreads();
    if (t < 256) {
        int m = t >> 4, n = t & 15;
        float sv = 0.f;
        #pragma unroll
        for (int w8 = 0; w8 < 8; ++w8) sv += sp[w8][m][n];
        ss[m][n] = sv * zi[n >> 3];
    }
    __syncthreads();
    if (t < 32) {
        int m = t >> 1, ll = t & 1;
        float sq = 0.f;
        #pragma unroll
        for (int o = 0; o < 8; ++o) { float e = ss[m][ll * 8 + o]; sq += e * e; }
        facs[m][ll] = sqrtf(sq) / (1.0f + sq);   // == (sq/(1+sq))/norm; pad adds 0
    }
    __syncthreads();
    if (t < 256) {
        int m = t >> 4, n = t & 15;
        int o = n & 7, lg = ng * 2 + (n >> 3);
        if (o < 7) {
            float vv = ss[m][n] * facs[m][n >> 3];
            vT[(size_t)(o * 16 + lg) * NB + b0 + m] = f2bf(vv);
            if (wout) out[(size_t)(b0 + m) * NLO + o * 16 + lg] = vv;
        }
    }
}

// ---- g_wc: G-MFMA + w-contraction + block-local bij update + eb=exp + Z
//      + wps rescale for the next iteration. 144 blocks x 512 threads. ----
// block owns i = blockIdx.x*8 .. +7 (ik = 64*bid .. +63) exclusively ->
// plain bij/wps writes, atomics only on Z.
__global__ __launch_bounds__(512) void g_wc(const ushort* __restrict__ xT,
                                            const ushort* __restrict__ vT,
                                            const float* __restrict__ w,
                                            float* __restrict__ bij,
                                            const ushort* __restrict__ wpT,
                                            ushort* __restrict__ wps,
                                            float* __restrict__ Zit, int accum) {
    __shared__ float bs[2][8][16];
    __shared__ float cs[128];
    int t = threadIdx.x;
    int wv = t >> 6;                 // 0..7
    int lane = t & 63;
    int half = wv & 1;
    int mt = wv >> 1;                // 0..3
    int m0 = blockIdx.x * 64 + mt * 16;
    int kb0 = half * 256;
    int row = lane & 15, quad = lane >> 4;
    const ushort* ap = xT + (size_t)(m0 + row) * NB + kb0 + quad * 8;
    const ushort* bp = vT + (size_t)row * NB + kb0 + quad * 8;    // + nt*16*NB
    f32x4 acc[7];
    #pragma unroll
    for (int nt = 0; nt < 7; ++nt) acc[nt] = (f32x4){0.f, 0.f, 0.f, 0.f};
    // load-use interleave: one A-frag + one B-frag live at a time
    for (int ks = 0; ks < 8; ++ks) {                 // 256/32
        bf16x8 a = *(const bf16x8*)(ap + ks * 32);
        #pragma unroll
        for (int nt = 0; nt < 7; ++nt) {
            bf16x8 bfr = *(const bf16x8*)(bp + (size_t)nt * 16 * NB + ks * 32);
            acc[nt] = __builtin_amdgcn_mfma_f32_16x16x32_bf16(a, bfr, acc[nt], 0, 0, 0);
        }
    }
    // lane holds G[ik = m0+quad*4+r][o*16+l], o = nt, l = row
    float S = 0.f;
    #pragma unroll
    for (int r = 0; r < 4; ++r) {
        int ik = m0 + quad * 4 + r;
        const float* wr = w + (size_t)ik * NLO + row * 7;
        float p = 0.f;
        #pragma unroll
        for (int o = 0; o < 7; ++o) p += wr[o] * acc[o][r];
        S += p;
    }
    float Sp = __shfl_down(S, 16);                   // partner quad's 4-ik sum
    if ((quad & 1) == 0)
        bs[half][mt * 2 + (quad >> 1)][row] = (S + Sp) * (1.0f / 512.0f);
    __syncthreads();
    if (t < 128) {
        int il = t >> 4, l = t & 15;
        int i = blockIdx.x * 8 + il;
        float val = bs[0][il][l] + bs[1][il][l];
        if (accum) val += bij[i * 16 + l];
        bij[i * 16 + l] = val;
        cs[t] = expf(val);           // cs[il*16 + l]
    }
    __syncthreads();
    if (t < 16) {
        float z = 0.f;
        #pragma unroll
        for (int j = 0; j < 8; ++j) z += cs[j * 16 + t];
        atomicAdd(&Zit[t], z);
    }
    // rescale this block's 64 ik-columns: wps = bf16(cs * wpT) for next iter.
    int ik0 = blockIdx.x * 64;
    for (int e = t; e < 2048; e += 512) {
        int np = e >> 4, i4 = (e & 15) * 4;
        float sc = cs[(i4 >> 3) * 16 + (np >> 3)];
        ushort4 wv4 = *(const ushort4*)&wpT[(size_t)np * NIK + ik0 + i4];
        ushort4 o4 = { f2bf(bf2f((short)wv4.x) * sc), f2bf(bf2f((short)wv4.y) * sc),
                       f2bf(bf2f((short)wv4.z) * sc), f2bf(bf2f((short)wv4.w) * sc) };
        *(ushort4*)&wps[(size_t)np * NIK + ik0 + i4] = o4;
    }
}

extern "C" void kernel_launch(void* const* d_in, const int* in_sizes, int n_in,
                              void* d_out, int out_size, void* d_ws, size_t ws_size,
                              hipStream_t stream) {
    const float* x = (const float*)d_in[0];   // [512][9216]
    const float* w = (const float*)d_in[1];   // [9216][112]
    float* out = (float*)d_out;               // [512][112]
    float* ws = (float*)d_ws;
    float*  f_bij  = ws;                                  // 18432
    float*  f_Z    = f_bij + NI * 16;                     // 3*16
    ushort* xbf    = (ushort*)(f_Z + 48);                 // 512*9216
    ushort* xT     = xbf + (size_t)NB * NIK;              // 9216*512
    ushort* wpT    = xT + (size_t)NIK * NB;               // 128*9216 static
    ushort* wps    = wpT + (size_t)NPAD * NIK;            // 128*9216 scaled
    ushort* vT     = wps + (size_t)NPAD * NIK;            // 112*512
    prep0<<<1296, 256, 0, stream>>>(x, xbf, xT, w, wpT, wps, f_Z);
    for (int it = 0; it < 3; ++it) {
        sq_gemm<<<256, 512, 0, stream>>>(xbf, wps, f_Z + it * 16, vT, out,
                                         it == 2 ? 1 : 0);
        if (it < 2)
            g_wc<<<144, 512, 0, stream>>>(xT, vT, w, f_bij, wpT, wps,
                                          f_Z + (it + 1) * 16, it);
    }
}